// Round 9
// baseline (293.624 us; speedup 1.0000x reference)
//
#include <hip/hip_runtime.h>
#include <hip/hip_bf16.h>
#include <stdint.h>

#define B_SZ 4
#define C_IN 256
#define N_SP 4096
#define HEADS 4
#define DH 32
#define HID 128

#define BI 128      // queries per block (4 waves x 32)
#define BJ 64       // keys per body
#define NJH 2       // j-split count
#define JHSZ 2048   // keys per split
#define NB 32       // bodies per block = JHSZ/BJ
#define PP 68       // P LDS row pitch in shorts (136 B)

typedef short short4v __attribute__((ext_vector_type(4)));
typedef short short8 __attribute__((ext_vector_type(8)));
typedef float f32x4 __attribute__((ext_vector_type(4)));

#if __has_builtin(__builtin_amdgcn_exp2f)
#define EXP2 __builtin_amdgcn_exp2f
#else
#define EXP2 exp2f
#endif

__device__ __forceinline__ short f2bfs(float f) {  // round-half-up f32->bf16
  return (short)((__float_as_uint(f) + 0x8000u) >> 16);
}
__device__ __forceinline__ uint32_t pk_bf(float a, float b) {  // pack 2 bf16 (a=low)
  uint32_t ua = __float_as_uint(a) + 0x8000u;
  uint32_t ub = __float_as_uint(b) + 0x8000u;
  return (ua >> 16) | (ub & 0xffff0000u);
}
__device__ __forceinline__ short8 ld_frag(const short* p) {  // 8B-aligned 16B LDS read
  short4v a = *(const short4v*)p;
  short4v b = *(const short4v*)(p + 4);
  return __builtin_shufflevector(a, b, 0, 1, 2, 3, 4, 5, 6, 7);
}
__device__ __forceinline__ f32x4 mfma16(short8 a, short8 b, f32x4 c) {
  return __builtin_amdgcn_mfma_f32_16x16x32_bf16(a, b, c, 0, 0, 0);
}

// ---------------- Kernel 1: QKV projection, fused transpose ----------------
// grid (64 nb, 6 og, 4 b). Block: 64 qkv-rows x 64 n; thread: 4 rows x 4 cols.
__global__ __launch_bounds__(256) void qkv_proj_k(
    const float* __restrict__ x, const float* __restrict__ w,
    short* __restrict__ qt, short* __restrict__ kt, short* __restrict__ vt) {
  __shared__ short T2[64 * 68];  // [row][n] bf16, pitch 68
  const int t = threadIdx.x;
  const int tn = t & 15, tr = t >> 4;
  const int nb = blockIdx.x, og = blockIdx.y, b = blockIdx.z;
  const int n0 = nb * 64 + tn * 4;
  const int r0 = og * 64 + tr * 4;
  const float* xb = x + (size_t)b * C_IN * N_SP + n0;
  float acc[4][4];
#pragma unroll
  for (int r = 0; r < 4; ++r)
#pragma unroll
    for (int j = 0; j < 4; ++j) acc[r][j] = 0.f;
#pragma unroll 4
  for (int c = 0; c < C_IN; c += 2) {
    const float4 xa = *(const float4*)(xb + (size_t)c * N_SP);
    const float4 xc = *(const float4*)(xb + (size_t)(c + 1) * N_SP);
    const float xaj[4] = {xa.x, xa.y, xa.z, xa.w};
    const float xcj[4] = {xc.x, xc.y, xc.z, xc.w};
#pragma unroll
    for (int r = 0; r < 4; ++r) {
      const float2 wv = *(const float2*)(w + (size_t)(r0 + r) * C_IN + c);
#pragma unroll
      for (int j = 0; j < 4; ++j) acc[r][j] += wv.x * xaj[j] + wv.y * xcj[j];
    }
  }
  if (og >= 4) {  // V rows: [d][n] coalesced 8B stores
    const int d_all = og * 64 - 256 + tr * 4;
#pragma unroll
    for (int r = 0; r < 4; ++r) {
      const int h = (d_all + r) >> 5, d = (d_all + r) & 31;
      short4v p;
#pragma unroll
      for (int j = 0; j < 4; ++j) p[j] = f2bfs(acc[r][j]);
      *(short4v*)(vt + ((size_t)(b * HEADS + h) * DH + d) * N_SP + n0) = p;
    }
  } else {  // Q/K: LDS [row][n] tile, then coalesced [n][d] stores
    const int isK = og >> 1;
    const float sc = isK ? 1.f : (0.17677669529663687f * 1.4426950408889634f);
#pragma unroll
    for (int r = 0; r < 4; ++r) {
      short4v p;
#pragma unroll
      for (int j = 0; j < 4; ++j) p[j] = f2bfs(acc[r][j] * sc);
      *(short4v*)(T2 + (tr * 4 + r) * 68 + tn * 4) = p;
    }
    __syncthreads();
    const int hbase = (og & 1) * 2;
#pragma unroll
    for (int k = 0; k < 2; ++k) {
      const int g = t + 256 * k;               // chunk id, 512 total
      const int hh = g >> 8, rem = g & 255;
      const int n = rem >> 2, dq = rem & 3;    // col n, d-quarter
      short8 v;
#pragma unroll
      for (int e = 0; e < 8; ++e) v[e] = T2[(hh * 32 + dq * 8 + e) * 68 + n];
      short* dst = (isK ? kt : qt) +
                   ((size_t)(b * HEADS + hbase + hh) * N_SP + nb * 64 + n) * DH + dq * 8;
      *(short8*)dst = v;
    }
  }
}

// ---------------- Kernel 2: flash attention, deferred-P pipeline ----------------
// grid (32 ib, 16 bh, 2 jh). Unnormalized fp32 O -> Oh[jh][bh*32+d][n], l -> lg.
// Body p: S(p) via mfma; read P(p-1) from LDS buf[(p-1)&1] (written a body ago,
// no hard wait); prefetch K(p+1), V(p); exp -> write buf[p&1]; PV with V(p-1).
__global__ __launch_bounds__(256, 3) void attn_k(
    const short* __restrict__ qt, const short* __restrict__ kt,
    const short* __restrict__ vt, float* __restrict__ Oh, float* __restrict__ lg) {
  __shared__ short Ps2[2][BI * PP];   // 2 x 17408 B, rows owned per-wave
  float* Osh = (float*)&Ps2[0][0];    // epilogue alias (buf0 dead by then), 16896 B
  const int t = threadIdx.x;
  const int lane = t & 63, w = t >> 6;
  const int l15 = lane & 15, quad = lane >> 4;
  const int i0 = blockIdx.x * BI;
  const int bh = blockIdx.y, jh = blockIdx.z;
  const int jbeg = jh * JHSZ;
  const short* qg = qt + ((size_t)bh * N_SP + i0) * DH;
  const short* kg = kt + (size_t)bh * N_SP * DH;
  const short* vg = vt + (size_t)bh * DH * N_SP;

  short8 bq[2];
#pragma unroll
  for (int tt = 0; tt < 2; ++tt)
    bq[tt] = *(const short8*)(qg + (size_t)(w * 32 + tt * 16 + l15) * DH + quad * 8);

  const f32x4 zz = {0.f, 0.f, 0.f, 0.f};
  f32x4 o_acc[2][2] = {{zz, zz}, {zz, zz}};
  float lsum[2] = {0.f, 0.f};
  int rowoff[2];
#pragma unroll
  for (int tt = 0; tt < 2; ++tt) rowoff[tt] = (w * 32 + tt * 16 + l15) * PP;

  short8 akA[4], akB[4], vbA[2][2], vbB[2][2];

  auto loadK = [&](short8 (&ak)[4], int j) {
#pragma unroll
    for (int jt = 0; jt < 4; ++jt)
      ak[jt] = *(const short8*)(kg + (size_t)(j + jt * 16 + l15) * DH + quad * 8);
  };
  auto loadV = [&](short8 (&vb)[2][2], int j) {
#pragma unroll
    for (int dt = 0; dt < 2; ++dt)
#pragma unroll
      for (int kk = 0; kk < 2; ++kk)
        vb[dt][kk] = *(const short8*)(vg + (size_t)(dt * 16 + l15) * N_SP + j + kk * 32 + quad * 8);
  };
  auto expwrite = [&](f32x4 (&sf)[2][4], short* bufw) {
#pragma unroll
    for (int tt = 0; tt < 2; ++tt)
#pragma unroll
      for (int jt = 0; jt < 4; ++jt) {
        const float e0 = EXP2(sf[tt][jt][0]);
        const float e1 = EXP2(sf[tt][jt][1]);
        const float e2 = EXP2(sf[tt][jt][2]);
        const float e3 = EXP2(sf[tt][jt][3]);
        lsum[tt] += (e0 + e1) + (e2 + e3);
        uint2 pk; pk.x = pk_bf(e0, e1); pk.y = pk_bf(e2, e3);
        *(uint2*)(bufw + rowoff[tt] + jt * 16 + quad * 4) = pk;
      }
  };
  auto readP = [&](short8 (&pa)[2][2], const short* bufr) {
#pragma unroll
    for (int tt = 0; tt < 2; ++tt)
#pragma unroll
      for (int kk = 0; kk < 2; ++kk)
        pa[tt][kk] = ld_frag(bufr + rowoff[tt] + kk * 32 + quad * 8);
  };

  // body p: S from akc; read P(p-1) from bufr; prefetch K(p+1)->akn, V(p)->vbc;
  // exp->bufw; PV with V(p-1)=vbp.
  auto body = [&](short8 (&akc)[4], short8 (&akn)[4],
                  short8 (&vbp)[2][2], short8 (&vbc)[2][2],
                  short* bufw, const short* bufr, int jk, int jv, bool doK) {
    f32x4 sf[2][4];
#pragma unroll
    for (int tt = 0; tt < 2; ++tt)
#pragma unroll
      for (int jt = 0; jt < 4; ++jt) sf[tt][jt] = mfma16(akc[jt], bq[tt], zz);
    short8 pa[2][2];
    readP(pa, bufr);
    if (doK) loadK(akn, jk);
    loadV(vbc, jv);
    expwrite(sf, bufw);
#pragma unroll
    for (int tt = 0; tt < 2; ++tt)
#pragma unroll
      for (int dt = 0; dt < 2; ++dt) {
        o_acc[tt][dt] = mfma16(pa[tt][0], vbp[dt][0], o_acc[tt][dt]);
        o_acc[tt][dt] = mfma16(pa[tt][1], vbp[dt][1], o_acc[tt][dt]);
      }
  };

  // prologue + body0 (even; no PV, writes buf0, loads K1->akB, V0->vbB)
  loadK(akA, jbeg);
  {
    f32x4 sf[2][4];
#pragma unroll
    for (int tt = 0; tt < 2; ++tt)
#pragma unroll
      for (int jt = 0; jt < 4; ++jt) sf[tt][jt] = mfma16(akA[jt], bq[tt], zz);
    loadK(akB, jbeg + BJ);
    loadV(vbB, jbeg);
    expwrite(sf, &Ps2[0][0]);
  }
  int jcur = jbeg + BJ;  // j of next body (body1, odd)
  for (int it = 0; it < (NB - 2) / 2; ++it) {  // bodies 1..30
    body(akB, akA, vbB, vbA, &Ps2[1][0], &Ps2[0][0], jcur + BJ, jcur, true);
    jcur += BJ;
    body(akA, akB, vbA, vbB, &Ps2[0][0], &Ps2[1][0], jcur + BJ, jcur, true);
    jcur += BJ;
  }
  // body31 (odd; no K prefetch)
  body(akB, akA, vbB, vbA, &Ps2[1][0], &Ps2[0][0], jbeg, jcur, false);
  // final PV: P(31) x V(31)=vbA
  {
    short8 pa[2][2];
    readP(pa, &Ps2[1][0]);
#pragma unroll
    for (int tt = 0; tt < 2; ++tt)
#pragma unroll
      for (int dt = 0; dt < 2; ++dt) {
        o_acc[tt][dt] = mfma16(pa[tt][0], vbA[dt][0], o_acc[tt][dt]);
        o_acc[tt][dt] = mfma16(pa[tt][1], vbA[dt][1], o_acc[tt][dt]);
      }
  }

  // l partial sums
#pragma unroll
  for (int tt = 0; tt < 2; ++tt) {
    lsum[tt] += __shfl_xor(lsum[tt], 16);
    lsum[tt] += __shfl_xor(lsum[tt], 32);
  }
  if (quad == 0) {
    float* lgp = lg + ((size_t)jh * 16 + bh) * N_SP + i0;
    lgp[w * 32 + l15] = lsum[0];
    lgp[w * 32 + 16 + l15] = lsum[1];
  }
  __syncthreads();  // all waves done with Ps2[0] before Osh reuse
#pragma unroll
  for (int tt = 0; tt < 2; ++tt)
#pragma unroll
    for (int dt = 0; dt < 2; ++dt)
#pragma unroll
      for (int r = 0; r < 4; ++r)
        Osh[(dt * 16 + l15) * 132 + w * 32 + tt * 16 + quad * 4 + r] = o_acc[tt][dt][r];
  __syncthreads();
  {
    const int d = t >> 3, ch = t & 7;
    float* dst = Oh + ((size_t)jh * 512 + bh * DH + d) * N_SP + i0 + ch * 16;
    const float* src = Osh + d * 132 + ch * 16;
#pragma unroll
    for (int k2 = 0; k2 < 4; ++k2) *(float4*)(dst + k2 * 4) = *(const float4*)(src + k2 * 4);
  }
}

// ---------------- Kernel 3: combine halves + normalize + output projection ---------
__global__ __launch_bounds__(256) void out_proj_k(
    const float* __restrict__ Oh, const float* __restrict__ lg,
    const float* __restrict__ w, const float* __restrict__ bias,
    float* __restrict__ out) {
  const int t = threadIdx.x;
  const int n0 = blockIdx.x * 512 + t * 2;
  const int o0 = blockIdx.y * 8;
  const int b = blockIdx.z;
  float inv[4][2];
#pragma unroll
  for (int h = 0; h < 4; ++h) {
    const float2 a = *(const float2*)(lg + (size_t)(b * 4 + h) * N_SP + n0);
    const float2 c = *(const float2*)(lg + (size_t)(16 + b * 4 + h) * N_SP + n0);
    inv[h][0] = 1.f / (a.x + c.x);
    inv[h][1] = 1.f / (a.y + c.y);
  }
  const float* O0 = Oh + (size_t)(b * HID) * N_SP;
  const float* O1 = O0 + (size_t)512 * N_SP;
  float acc[8][2];
#pragma unroll
  for (int r = 0; r < 8; ++r) { acc[r][0] = 0.f; acc[r][1] = 0.f; }
#pragma unroll 4
  for (int c = 0; c < HID; c += 2) {
    const int h = c >> 5;
    const float2 p0 = *(const float2*)(O0 + (size_t)c * N_SP + n0);
    const float2 q0 = *(const float2*)(O1 + (size_t)c * N_SP + n0);
    const float2 p1 = *(const float2*)(O0 + (size_t)(c + 1) * N_SP + n0);
    const float2 q1 = *(const float2*)(O1 + (size_t)(c + 1) * N_SP + n0);
    const float a00 = (p0.x + q0.x) * inv[h][0], a01 = (p0.y + q0.y) * inv[h][1];
    const float a10 = (p1.x + q1.x) * inv[h][0], a11 = (p1.y + q1.y) * inv[h][1];
#pragma unroll
    for (int r = 0; r < 8; ++r) {
      const float2 wv = *(const float2*)(w + (size_t)(o0 + r) * HID + c);
      acc[r][0] += wv.x * a00 + wv.y * a10;
      acc[r][1] += wv.x * a01 + wv.y * a11;
    }
  }
#pragma unroll
  for (int r = 0; r < 8; ++r) {
    const float bv = bias[o0 + r];
    *(float2*)(out + ((size_t)b * C_IN + o0 + r) * N_SP + n0) =
        make_float2(acc[r][0] + bv, acc[r][1] + bv);
  }
}

extern "C" void kernel_launch(void* const* d_in, const int* in_sizes, int n_in,
                              void* d_out, int out_size, void* d_ws, size_t ws_size,
                              hipStream_t stream) {
  const float* x = (const float*)d_in[0];
  const float* w_qkv = (const float*)d_in[1];
  const float* w_out = (const float*)d_in[2];
  const float* b_out = (const float*)d_in[3];
  float* out = (float*)d_out;

  short* qt = (short*)d_ws;                              // 16*4096*32 bf16 = 4 MB
  short* kt = qt + (size_t)16 * N_SP * DH;               // 4 MB
  short* vt = kt + (size_t)16 * N_SP * DH;               // 4 MB
  float* Oh = (float*)(vt + (size_t)16 * N_SP * DH);     // 2*512*4096 fp32 = 16.8 MB
  float* lg = Oh + (size_t)NJH * 512 * N_SP;             // 2*16*4096 fp32 = 512 KB

  qkv_proj_k<<<dim3(64, 6, B_SZ), 256, 0, stream>>>(x, w_qkv, qt, kt, vt);
  attn_k<<<dim3(N_SP / BI, 16, NJH), 256, 0, stream>>>(qt, kt, vt, Oh, lg);
  out_proj_k<<<dim3(8, 32, B_SZ), 256, 0, stream>>>(Oh, lg, w_out, b_out, out);
}

// Round 11
// 254.242 us; speedup vs baseline: 1.1549x; 1.1549x over previous
//
#include <hip/hip_runtime.h>
#include <hip/hip_bf16.h>
#include <stdint.h>

#define B_SZ 4
#define C_IN 256
#define N_SP 4096
#define HEADS 4
#define DH 32
#define HID 128

#define BI 128      // queries per block (4 waves x 32)
#define BJ 64       // keys per body
#define NJH 2       // j-split count
#define JHSZ 2048   // keys per split
#define NB 32       // bodies per block
#define PP 72       // P LDS row pitch in shorts (144 B, 16B-aligned rows, 2-way banks)

typedef short short2v __attribute__((ext_vector_type(2)));
typedef short short4v __attribute__((ext_vector_type(4)));
typedef short short8 __attribute__((ext_vector_type(8)));
typedef float f32x4 __attribute__((ext_vector_type(4)));

#if __has_builtin(__builtin_amdgcn_exp2f)
#define EXP2 __builtin_amdgcn_exp2f
#else
#define EXP2 exp2f
#endif

__device__ __forceinline__ short f2bfs(float f) {  // round-half-up f32->bf16
  return (short)((__float_as_uint(f) + 0x8000u) >> 16);
}
__device__ __forceinline__ uint32_t pk_bf(float a, float b) {  // pack 2 bf16 (a=low)
  uint32_t ua = __float_as_uint(a) + 0x8000u;
  uint32_t ub = __float_as_uint(b) + 0x8000u;
  return (ua >> 16) | (ub & 0xffff0000u);
}
__device__ __forceinline__ float bf_lo(uint32_t u) { return __uint_as_float(u << 16); }
__device__ __forceinline__ float bf_hi(uint32_t u) { return __uint_as_float(u & 0xffff0000u); }
__device__ __forceinline__ f32x4 mfma16(short8 a, short8 b, f32x4 c) {
  return __builtin_amdgcn_mfma_f32_16x16x32_bf16(a, b, c, 0, 0, 0);
}

// ---------------- Kernel 1: QKV projection (w scalarized; direct bf16 layouts) -------
// grid (8 nb, 24 og, 4 b). Block: 16 uniform qkv-rows x 512 n; thread: 2 cols.
// Q -> qt[bh][n][32] (scale*log2e folded), K -> kt[bh][n][32], V -> vt[bh][d][n].
__global__ __launch_bounds__(256) void qkv_proj_k(
    const float* __restrict__ x, const float* __restrict__ w,
    short* __restrict__ qt, short* __restrict__ kt, short* __restrict__ vt) {
  const int t = threadIdx.x;
  const int n0 = blockIdx.x * 512 + t * 2;
  const int r0 = blockIdx.y * 16;  // uniform across block -> w loads scalarize
  const int b = blockIdx.z;
  const float* xb = x + (size_t)b * C_IN * N_SP + n0;
  float acc[16][2];
#pragma unroll
  for (int r = 0; r < 16; ++r) { acc[r][0] = 0.f; acc[r][1] = 0.f; }
#pragma unroll 2
  for (int c = 0; c < C_IN; c += 2) {
    const float2 xa = *(const float2*)(xb + (size_t)c * N_SP);
    const float2 xc = *(const float2*)(xb + (size_t)(c + 1) * N_SP);
#pragma unroll
    for (int r = 0; r < 16; ++r) {
      const float2 wv = *(const float2*)(w + (size_t)(r0 + r) * C_IN + c);
      acc[r][0] += wv.x * xa.x + wv.y * xc.x;
      acc[r][1] += wv.x * xa.y + wv.y * xc.y;
    }
  }
  const int sect = r0 >> 7;          // 0=Q 1=K 2=V
  const int rr = r0 & 127;
  const int h = rr >> 5, d0 = rr & 31;
  const int bh = b * HEADS + h;
  if (sect == 2) {  // V: [d][n] coalesced 4B stores
#pragma unroll
    for (int r = 0; r < 16; ++r) {
      short2v p; p[0] = f2bfs(acc[r][0]); p[1] = f2bfs(acc[r][1]);
      *(short2v*)(vt + ((size_t)bh * DH + d0 + r) * N_SP + n0) = p;
    }
  } else {  // Q/K: [n][32] direct, 16B stores (d0 in {0,16})
    const float sc = sect ? 1.f : (0.17677669529663687f * 1.4426950408889634f);
    short* dst = (sect ? kt : qt) + (size_t)bh * N_SP * DH;
#pragma unroll
    for (int j = 0; j < 2; ++j) {
      short8 v0, v1;
#pragma unroll
      for (int e = 0; e < 8; ++e) {
        v0[e] = f2bfs(acc[e][j] * sc);
        v1[e] = f2bfs(acc[8 + e][j] * sc);
      }
      short* p = dst + (size_t)(n0 + j) * DH + d0;
      *(short8*)p = v0;
      *(short8*)(p + 8) = v1;
    }
  }
}

// ---------------- Kernel 2: flash attention, slim issue stream ----------------
// grid (32 ib, 16 bh, 2 jh). Raw fp32 O -> Oh[jh][bh*32+d][n]; l (=P·1 via MFMA) -> lg.
__global__ __launch_bounds__(256, 3) void attn_k(
    const short* __restrict__ qt, const short* __restrict__ kt,
    const short* __restrict__ vt, float* __restrict__ Oh, float* __restrict__ lg) {
  __shared__ short Ps[BI * PP];   // 18432 B, rows owned per-wave
  float* Osh = (float*)Ps;        // epilogue alias (after barrier)
  const int t = threadIdx.x;
  const int lane = t & 63, w = t >> 6;
  const int l15 = lane & 15, quad = lane >> 4;
  const int i0 = blockIdx.x * BI;
  const int bh = blockIdx.y, jh = blockIdx.z;
  const int jbeg = jh * JHSZ;
  const short* qg = qt + ((size_t)bh * N_SP + i0) * DH;

  short8 bq[2];
#pragma unroll
  for (int tt = 0; tt < 2; ++tt)
    bq[tt] = *(const short8*)(qg + (tt * 16 + w * 32 + l15) * DH + quad * 8);

  const f32x4 zz = {0.f, 0.f, 0.f, 0.f};
  f32x4 o_acc[2][2] = {{zz, zz}, {zz, zz}};
  f32x4 l_acc[2] = {zz, zz};
  short8 ones;
#pragma unroll
  for (int e = 0; e < 8; ++e) ones[e] = (short)0x3F80;  // bf16 1.0

  // lane-invariant offsets (in shorts)
  const int koff = l15 * DH + quad * 8;
  int voff[2];
#pragma unroll
  for (int dt = 0; dt < 2; ++dt) voff[dt] = (dt * 16 + l15) * N_SP + quad * 8;
  int rowoff[2];
#pragma unroll
  for (int tt = 0; tt < 2; ++tt) rowoff[tt] = (w * 32 + tt * 16 + l15) * PP;

  const short* kgj = kt + (size_t)bh * N_SP * DH + jbeg * DH;
  const short* vgj = vt + (size_t)bh * DH * N_SP + jbeg;
  short8 akA[4], akB[4];
#pragma unroll
  for (int jt = 0; jt < 4; ++jt) akA[jt] = *(const short8*)(kgj + jt * 512 + koff);

#define BODY(CUR, NXT)                                                          \
  {                                                                             \
    f32x4 sf[2][4];                                                             \
    _Pragma("unroll") for (int tt = 0; tt < 2; ++tt)                            \
        _Pragma("unroll") for (int jt = 0; jt < 4; ++jt)                        \
            sf[tt][jt] = mfma16(CUR[jt], bq[tt], zz);                           \
    kgj += BJ * DH;                                                             \
    _Pragma("unroll") for (int jt = 0; jt < 4; ++jt)                            \
        NXT[jt] = *(const short8*)(kgj + jt * 512 + koff);                      \
    short8 vb[2][2];                                                            \
    _Pragma("unroll") for (int dt = 0; dt < 2; ++dt)                            \
        _Pragma("unroll") for (int kk = 0; kk < 2; ++kk)                        \
            vb[dt][kk] = *(const short8*)(vgj + voff[dt] + kk * 32);            \
    vgj += BJ;                                                                  \
    _Pragma("unroll") for (int tt = 0; tt < 2; ++tt)                            \
        _Pragma("unroll") for (int jt = 0; jt < 4; ++jt) {                      \
      const float e0 = EXP2(sf[tt][jt][0]);                                     \
      const float e1 = EXP2(sf[tt][jt][1]);                                     \
      const float e2 = EXP2(sf[tt][jt][2]);                                     \
      const float e3 = EXP2(sf[tt][jt][3]);                                     \
      uint2 pk; pk.x = pk_bf(e0, e1); pk.y = pk_bf(e2, e3);                     \
      *(uint2*)(Ps + rowoff[tt] + jt * 16 + quad * 4) = pk;                     \
    }                                                                           \
    asm volatile("s_waitcnt lgkmcnt(0)" ::: "memory");                          \
    short8 pa[2][2];                                                            \
    _Pragma("unroll") for (int tt = 0; tt < 2; ++tt)                            \
        _Pragma("unroll") for (int kk = 0; kk < 2; ++kk)                        \
            pa[tt][kk] = *(const short8*)(Ps + rowoff[tt] + kk * 32 + quad * 8);\
    _Pragma("unroll") for (int tt = 0; tt < 2; ++tt) {                          \
      o_acc[tt][0] = mfma16(pa[tt][0], vb[0][0], o_acc[tt][0]);                 \
      o_acc[tt][0] = mfma16(pa[tt][1], vb[0][1], o_acc[tt][0]);                 \
      o_acc[tt][1] = mfma16(pa[tt][0], vb[1][0], o_acc[tt][1]);                 \
      o_acc[tt][1] = mfma16(pa[tt][1], vb[1][1], o_acc[tt][1]);                 \
      l_acc[tt] = mfma16(pa[tt][0], ones, l_acc[tt]);                           \
      l_acc[tt] = mfma16(pa[tt][1], ones, l_acc[tt]);                           \
    }                                                                           \
  }

  for (int p = 0; p < NB; p += 2) {
    BODY(akA, akB)
    BODY(akB, akA)
  }
#undef BODY

  // l: l_acc[tt][r] = rowsum for i = w*32+tt*16+quad*4+r (all cols identical)
  if (l15 == 0) {
    float* lgp = lg + ((size_t)jh * 16 + bh) * N_SP + i0;
#pragma unroll
    for (int tt = 0; tt < 2; ++tt)
#pragma unroll
      for (int r = 0; r < 4; ++r) lgp[w * 32 + tt * 16 + quad * 4 + r] = l_acc[tt][r];
  }
  __syncthreads();  // everyone done with Ps before Osh alias
#pragma unroll
  for (int tt = 0; tt < 2; ++tt)
#pragma unroll
    for (int dt = 0; dt < 2; ++dt)
#pragma unroll
      for (int r = 0; r < 4; ++r)
        Osh[(dt * 16 + l15) * 132 + w * 32 + tt * 16 + quad * 4 + r] = o_acc[tt][dt][r];
  __syncthreads();
  {
    const int d = t >> 3, ch = t & 7;
    float* dst = Oh + ((size_t)jh * 512 + bh * DH + d) * N_SP + i0 + ch * 16;
    const float* src = Osh + d * 132 + ch * 16;
#pragma unroll
    for (int k2 = 0; k2 < 4; ++k2) *(float4*)(dst + k2 * 4) = *(const float4*)(src + k2 * 4);
  }
}

// ---------------- Kernel 2b: combine halves + normalize -> bf16 att ----------------
// grid (4 nb, 512 rows). att[b][h*32+d][n] = (Oh0+Oh1) / (l0+l1)
__global__ __launch_bounds__(256) void combine_k(
    const float* __restrict__ Oh, const float* __restrict__ lg,
    short* __restrict__ att) {
  const int t = threadIdx.x;
  const int row = blockIdx.y;           // b*128 + h*32 + d
  const int b = row >> 7, hd = row & 127;
  const int bh = b * HEADS + (hd >> 5), d = hd & 31;
  const int n = blockIdx.x * 1024 + t * 4;
  const float4 o0 = *(const float4*)(Oh + ((size_t)bh * DH + d) * N_SP + n);
  const float4 o1 = *(const float4*)(Oh + ((size_t)(512 + bh * DH + d)) * N_SP + n);
  const float4 l0 = *(const float4*)(lg + (size_t)bh * N_SP + n);
  const float4 l1 = *(const float4*)(lg + (size_t)(16 + bh) * N_SP + n);
  short4v p;
  p[0] = f2bfs((o0.x + o1.x) / (l0.x + l1.x));
  p[1] = f2bfs((o0.y + o1.y) / (l0.y + l1.y));
  p[2] = f2bfs((o0.z + o1.z) / (l0.z + l1.z));
  p[3] = f2bfs((o0.w + o1.w) / (l0.w + l1.w));
  *(short4v*)(att + (size_t)row * N_SP + n) = p;
}

// ---------------- Kernel 3: output projection + bias (bf16 att in, fp32 out) --------
// grid (8 nb, 16 og, 4 b). 16 uniform w-rows (scalarized) x 512 n.
__global__ __launch_bounds__(256) void out_proj_k(
    const short* __restrict__ att, const float* __restrict__ w,
    const float* __restrict__ bias, float* __restrict__ out) {
  const int t = threadIdx.x;
  const int n0 = blockIdx.x * 512 + t * 2;
  const int o0 = blockIdx.y * 16;
  const int b = blockIdx.z;
  const short* ab = att + (size_t)b * HID * N_SP + n0;
  float acc[16][2];
#pragma unroll
  for (int r = 0; r < 16; ++r) { acc[r][0] = 0.f; acc[r][1] = 0.f; }
#pragma unroll 2
  for (int c = 0; c < HID; c += 2) {
    const uint32_t u0 = *(const uint32_t*)(ab + (size_t)c * N_SP);
    const uint32_t u1 = *(const uint32_t*)(ab + (size_t)(c + 1) * N_SP);
    const float a00 = bf_lo(u0), a01 = bf_hi(u0);
    const float a10 = bf_lo(u1), a11 = bf_hi(u1);
#pragma unroll
    for (int r = 0; r < 16; ++r) {
      const float2 wv = *(const float2*)(w + (size_t)(o0 + r) * HID + c);
      acc[r][0] += wv.x * a00 + wv.y * a10;
      acc[r][1] += wv.x * a01 + wv.y * a11;
    }
  }
#pragma unroll
  for (int r = 0; r < 16; ++r) {
    const float bv = bias[o0 + r];
    *(float2*)(out + ((size_t)b * C_IN + o0 + r) * N_SP + n0) =
        make_float2(acc[r][0] + bv, acc[r][1] + bv);
  }
}

extern "C" void kernel_launch(void* const* d_in, const int* in_sizes, int n_in,
                              void* d_out, int out_size, void* d_ws, size_t ws_size,
                              hipStream_t stream) {
  const float* x = (const float*)d_in[0];
  const float* w_qkv = (const float*)d_in[1];
  const float* w_out = (const float*)d_in[2];
  const float* b_out = (const float*)d_in[3];
  float* out = (float*)d_out;

  short* qt = (short*)d_ws;                              // 4 MB
  short* kt = qt + (size_t)16 * N_SP * DH;               // 4 MB
  short* vt = kt + (size_t)16 * N_SP * DH;               // 4 MB
  float* Oh = (float*)(vt + (size_t)16 * N_SP * DH);     // 2*512*4096 fp32 = 16.8 MB
  float* lg = Oh + (size_t)NJH * 512 * N_SP;             // 512 KB
  short* att = qt;                                       // alias: qt/kt dead after attn

  qkv_proj_k<<<dim3(8, 24, B_SZ), 256, 0, stream>>>(x, w_qkv, qt, kt, vt);
  attn_k<<<dim3(N_SP / BI, 16, NJH), 256, 0, stream>>>(qt, kt, vt, Oh, lg);
  combine_k<<<dim3(4, 512), 256, 0, stream>>>(Oh, lg, att);
  out_proj_k<<<dim3(8, 16, B_SZ), 256, 0, stream>>>(att, w_out, b_out, out);
}